// Round 4
// baseline (190.228 us; speedup 1.0000x reference)
//
#include <hip/hip_runtime.h>

#define BATCH 2
#define SEQ   4096
#define DIM   256
#define NHEAD 8
#define HDIM  32
#define ROWS  (BATCH * SEQ)   // 8192

typedef __attribute__((ext_vector_type(8))) short short8;
typedef __attribute__((ext_vector_type(4))) unsigned short ushortx4;
typedef __attribute__((ext_vector_type(4))) float floatx4;
typedef __attribute__((ext_vector_type(2))) unsigned int uintx2;

static __device__ __forceinline__ unsigned short f2bf(float f) {
    union { float f; unsigned u; } v; v.f = f;
    unsigned r = v.u + 0x7fffu + ((v.u >> 16) & 1u);   // RNE
    return (unsigned short)(r >> 16);
}
static __device__ __forceinline__ unsigned fbits(float f) {
    union { float f; unsigned u; } v; v.f = f; return v.u;
}
// pack two fp32 -> two bf16 (truncate) in ONE v_perm_b32
static __device__ __forceinline__ unsigned pack2(float a, float b) {
    return __builtin_amdgcn_perm(fbits(b), fbits(a), 0x07060302u);
}
// async global -> LDS: wave-uniform LDS base + lane*16
static __device__ __forceinline__ void g2l16(const void* g, void* l) {
    __builtin_amdgcn_global_load_lds(
        (const __attribute__((address_space(1))) unsigned int*)g,
        (__attribute__((address_space(3))) unsigned int*)l, 16, 0, 0);
}

// ---------------- fp32 -> bf16 conversion: x, y, Wq, Wk, Wv, Wo -------------
__global__ __launch_bounds__(256) void convert_kernel(
    const float* __restrict__ x, const float* __restrict__ y,
    const float* __restrict__ Wq, const float* __restrict__ Wk,
    const float* __restrict__ Wv, const float* __restrict__ Wo,
    unsigned short* __restrict__ xb, unsigned short* __restrict__ yb,
    unsigned short* __restrict__ Wqb, unsigned short* __restrict__ Wkb,
    unsigned short* __restrict__ Wvb, unsigned short* __restrict__ Wob) {
    const long NX = (long)ROWS * DIM;   // 2097152
    const long NW = (long)DIM * DIM;    // 65536
    long e0 = ((long)blockIdx.x * 256 + threadIdx.x) * 4;
    const float* src; unsigned short* dst; long off;
    if      (e0 < NX)          { src = x;  dst = xb;  off = e0; }
    else if (e0 < 2*NX)        { src = y;  dst = yb;  off = e0 - NX; }
    else if (e0 < 2*NX + NW)   { src = Wq; dst = Wqb; off = e0 - 2*NX; }
    else if (e0 < 2*NX + 2*NW) { src = Wk; dst = Wkb; off = e0 - 2*NX - NW; }
    else if (e0 < 2*NX + 3*NW) { src = Wv; dst = Wvb; off = e0 - 2*NX - 2*NW; }
    else if (e0 < 2*NX + 4*NW) { src = Wo; dst = Wob; off = e0 - 2*NX - 3*NW; }
    else return;
    float4 v = *(const float4*)(src + off);
    ushortx4 o;
    o.x = f2bf(v.x); o.y = f2bf(v.y); o.z = f2bf(v.z); o.w = f2bf(v.w);
    *(ushortx4*)(dst + off) = o;
}

// ---------------- QKV projection (all-bf16, LDS dbuf staging) ---------------
// grid (ROWS/64, 2, 3): 64m x 128n tile per block; wave = 32m x 64n.
// mat 0: q = (x@Wq^T+bq)*scale (scale=(1/16)*log2 e); mat 1: k; mat 2: vT transposed.
__global__ __launch_bounds__(256, 2) void qkv_kernel(
    const unsigned short* __restrict__ xb, const unsigned short* __restrict__ yb,
    const unsigned short* __restrict__ Wq, const unsigned short* __restrict__ Wk,
    const unsigned short* __restrict__ Wv,
    const float* __restrict__ bq, const float* __restrict__ bk, const float* __restrict__ bv,
    unsigned short* __restrict__ qo, unsigned short* __restrict__ ko,
    unsigned short* __restrict__ vto) {
    __shared__ unsigned short Ab0[64 * 32], Ab1[64 * 32];
    const int tid = threadIdx.x, lane = tid & 63, wave = tid >> 6;
    const int ql = lane & 15, quad = lane >> 4;
    const int wm = wave & 1, wn = wave >> 1;
    const int mat = blockIdx.z;
    const int m0 = blockIdx.x * 64;
    const int n0 = blockIdx.y * 128;
    const unsigned short* A = (mat == 0) ? xb : yb;
    const unsigned short* W = (mat == 0) ? Wq : (mat == 1) ? Wk : Wv;
    const float* bias = (mat == 0) ? bq : (mat == 1) ? bk : bv;

    // staging: wave stages rows [16w,16w+16) of the 64x32 k-slab
    const unsigned short* ag = A + (long)(m0 + wave*16 + (lane >> 2)) * DIM
                                 + ((lane & 3) ^ ((lane >> 3) & 3)) * 8;
    unsigned short* ad0 = Ab0 + wave * 512;
    unsigned short* ad1 = Ab1 + wave * 512;
    const int akey = (quad ^ ((ql >> 1) & 3)) * 8;

    floatx4 acc[2][4] = {};
    g2l16(ag, ad0);
    __syncthreads();
    for (int kb = 0; kb < 8; kb++) {
        if (kb < 7) g2l16(ag + (kb + 1) * 32, (kb & 1) ? ad0 : ad1);
        const unsigned short* Ას = (kb & 1) ? Ab1 : Ab0;
        short8 wf[4], af[2];
#pragma unroll
        for (int u = 0; u < 4; u++)
            wf[u] = *(const short8*)(W + (long)(n0 + wn*64 + u*16 + ql) * DIM + kb*32 + quad*8);
#pragma unroll
        for (int t = 0; t < 2; t++)
            af[t] = *(const short8*)(Ას + (wm*32 + t*16 + ql) * 32 + akey);
        if (mat < 2) {
#pragma unroll
            for (int t = 0; t < 2; t++)
#pragma unroll
                for (int u = 0; u < 4; u++)
                    acc[t][u] = __builtin_amdgcn_mfma_f32_16x16x32_bf16(wf[u], af[t], acc[t][u], 0, 0, 0);
        } else {
#pragma unroll
            for (int t = 0; t < 2; t++)
#pragma unroll
                for (int u = 0; u < 4; u++)
                    acc[t][u] = __builtin_amdgcn_mfma_f32_16x16x32_bf16(af[t], wf[u], acc[t][u], 0, 0, 0);
        }
        __syncthreads();
    }
    if (mat < 2) {
        const float scale = (mat == 0) ? 0.09016844005556021f : 1.0f;
        unsigned short* out = (mat == 0) ? qo : ko;
#pragma unroll
        for (int t = 0; t < 2; t++) {
            int m = m0 + wm*32 + t*16 + ql;
#pragma unroll
            for (int u = 0; u < 4; u++) {
                int n = n0 + wn*64 + u*16 + quad*4;
                float4 b4 = *(const float4*)(bias + n);
                ushortx4 o;
                o.x = f2bf((acc[t][u][0] + b4.x) * scale);
                o.y = f2bf((acc[t][u][1] + b4.y) * scale);
                o.z = f2bf((acc[t][u][2] + b4.z) * scale);
                o.w = f2bf((acc[t][u][3] + b4.w) * scale);
                *(ushortx4*)(out + (long)m * DIM + n) = o;
            }
        }
    } else {
#pragma unroll
        for (int t = 0; t < 2; t++) {
            int mb = m0 + wm*32 + t*16 + quad*4;
            int bi = mb >> 12, i0 = mb & (SEQ - 1);
#pragma unroll
            for (int u = 0; u < 4; u++) {
                int n = n0 + wn*64 + u*16 + ql;
                float b = bias[n];
                ushortx4 o;
                o.x = f2bf(acc[t][u][0] + b);
                o.y = f2bf(acc[t][u][1] + b);
                o.z = f2bf(acc[t][u][2] + b);
                o.w = f2bf(acc[t][u][3] + b);
                *(ushortx4*)(vto + ((long)(bi * DIM + n)) * SEQ + i0) = o;
            }
        }
    }
}

// ---------------- attention: 256-q blocks, 64 q/wave, kv-tile 64 dbuf -------
// LDS per q.kv unit: 6 B (vs 8 before). Swizzled staging, per-wave P, exp2
// softmax without max-subtraction, l via ones-MFMA.
__global__ __launch_bounds__(256, 1) void attn_kernel(
    const unsigned short* __restrict__ qb, const unsigned short* __restrict__ kbuf,
    const unsigned short* __restrict__ vT, unsigned short* __restrict__ ao) {
    __shared__ unsigned short K0[64 * 32], K1[64 * 32];
    __shared__ unsigned short V0[32 * 64], V1[32 * 64];
    __shared__ unsigned short P[4][64][72];
    const int tid = threadIdx.x, lane = tid & 63, wave = tid >> 6;
    const int ql = lane & 15, quad = lane >> 4;
    const int bh = blockIdx.y, b = bh >> 3, h = bh & 7;
    const int q0 = blockIdx.x * 256 + wave * 64;

    const unsigned short* qrow = qb   + (long)b * SEQ * DIM + h * HDIM;
    const unsigned short* krow = kbuf + (long)b * SEQ * DIM + h * HDIM;
    const unsigned short* vrow = vT   + (long)(b * DIM + h * HDIM) * SEQ;

    short8 qf[4];
#pragma unroll
    for (int t = 0; t < 4; t++)
        qf[t] = *(const short8*)(qrow + (long)(q0 + t*16 + ql) * DIM + quad*8);

    short8 ones;
#pragma unroll
    for (int i = 0; i < 8; i++) ones[i] = (short)0x3F80;

    // staging: this wave stages K rows [16w,16w+16) (32d=64B each, 4 chunks)
    // and V rows [8w,8w+8) (64kv=128B each, 8 chunks), both chunk-XOR swizzled.
    const unsigned short* kg = krow + (long)(wave*16 + (lane >> 2)) * DIM
                                    + ((lane & 3) ^ ((lane >> 3) & 3)) * 8;
    const unsigned short* vg = vrow + (long)(wave*8 + (lane >> 3)) * SEQ
                                    + ((lane & 7) ^ (lane >> 3)) * 8;
    unsigned short* kd0 = K0 + wave * 512;  unsigned short* kd1 = K1 + wave * 512;
    unsigned short* vd0 = V0 + wave * 512;  unsigned short* vd1 = V1 + wave * 512;
    const int kro = (quad ^ ((ql >> 1) & 3)) * 8;   // K read chunk pos
    const int vmask = ql & 7;                        // V read xor key

    floatx4 acc[2][4] = {};    // O^T accum [dim-tile][q-tile]
    floatx4 accL[4] = {};      // row-sums via ones-MFMA

    auto compute = [&](const unsigned short* Ks, const unsigned short* Vs) {
#pragma unroll
        for (int mt = 0; mt < 4; ++mt) {
            short8 kf = *(const short8*)(Ks + (mt*16 + ql) * 32 + kro);
#pragma unroll
            for (int t = 0; t < 4; t++) {
                floatx4 z = {};
                floatx4 s = __builtin_amdgcn_mfma_f32_16x16x32_bf16(kf, qf[t], z, 0, 0, 0);
                float p0 = __builtin_amdgcn_exp2f(s[0]);
                float p1 = __builtin_amdgcn_exp2f(s[1]);
                float p2 = __builtin_amdgcn_exp2f(s[2]);
                float p3 = __builtin_amdgcn_exp2f(s[3]);
                uintx2 w;
                w.x = pack2(p0, p1);
                w.y = pack2(p2, p3);
                *(uintx2*)(&P[wave][t*16 + ql][mt*16 + quad*4]) = w;
            }
        }
#pragma unroll
        for (int ks = 0; ks < 2; ++ks) {
            short8 pf[4];
#pragma unroll
            for (int t = 0; t < 4; t++)
                pf[t] = *(const short8*)(&P[wave][t*16 + ql][ks*32 + quad*8]);
#pragma unroll
            for (int t = 0; t < 4; t++)
                accL[t] = __builtin_amdgcn_mfma_f32_16x16x32_bf16(ones, pf[t], accL[t], 0, 0, 0);
#pragma unroll
            for (int dt = 0; dt < 2; ++dt) {
                short8 vf = *(const short8*)(Vs + (dt*16 + ql) * 64 + ((ks*4 + quad) ^ vmask) * 8);
#pragma unroll
                for (int t = 0; t < 4; t++)
                    acc[dt][t] = __builtin_amdgcn_mfma_f32_16x16x32_bf16(vf, pf[t], acc[dt][t], 0, 0, 0);
            }
        }
    };

    g2l16(kg, kd0); g2l16(vg, vd0);
    __syncthreads();
    for (int it = 0; it < SEQ / 64; it += 2) {
        if (it + 1 < SEQ / 64) {
            g2l16(kg + (long)(it + 1) * 64 * DIM, kd1);
            g2l16(vg + (it + 1) * 64, vd1);
        }
        compute(K0, V0);
        __syncthreads();
        if (it + 2 < SEQ / 64) {
            g2l16(kg + (long)(it + 2) * 64 * DIM, kd0);
            g2l16(vg + (it + 2) * 64, vd0);
        }
        compute(K1, V1);
        __syncthreads();
    }

    float inv[4];
#pragma unroll
    for (int t = 0; t < 4; t++) inv[t] = 1.0f / accL[t][0];
#pragma unroll
    for (int dt = 0; dt < 2; dt++)
#pragma unroll
        for (int t = 0; t < 4; t++) {
            ushortx4 o;
            o.x = f2bf(acc[dt][t][0] * inv[t]);
            o.y = f2bf(acc[dt][t][1] * inv[t]);
            o.z = f2bf(acc[dt][t][2] * inv[t]);
            o.w = f2bf(acc[dt][t][3] * inv[t]);
            *(ushortx4*)(ao + (long)(b*SEQ + q0 + t*16 + ql) * DIM + h*HDIM + dt*16 + quad*4) = o;
        }
}

// ---------------- output projection: fp32 out --------------------------------
__global__ __launch_bounds__(256, 2) void oproj_kernel(
    const unsigned short* __restrict__ A, const unsigned short* __restrict__ W,
    const float* __restrict__ bias, float* __restrict__ out) {
    __shared__ unsigned short Ab0[64 * 32], Ab1[64 * 32];
    const int tid = threadIdx.x, lane = tid & 63, wave = tid >> 6;
    const int ql = lane & 15, quad = lane >> 4;
    const int wm = wave & 1, wn = wave >> 1;
    const int m0 = blockIdx.x * 64;
    const int n0 = blockIdx.y * 128;

    const unsigned short* ag = A + (long)(m0 + wave*16 + (lane >> 2)) * DIM
                                 + ((lane & 3) ^ ((lane >> 3) & 3)) * 8;
    unsigned short* ad0 = Ab0 + wave * 512;
    unsigned short* ad1 = Ab1 + wave * 512;
    const int akey = (quad ^ ((ql >> 1) & 3)) * 8;

    floatx4 acc[2][4] = {};
    g2l16(ag, ad0);
    __syncthreads();
    for (int kb = 0; kb < 8; kb++) {
        if (kb < 7) g2l16(ag + (kb + 1) * 32, (kb & 1) ? ad0 : ad1);
        const unsigned short* As = (kb & 1) ? Ab1 : Ab0;
        short8 wf[4], af[2];
#pragma unroll
        for (int u = 0; u < 4; u++)
            wf[u] = *(const short8*)(W + (long)(n0 + wn*64 + u*16 + ql) * DIM + kb*32 + quad*8);
#pragma unroll
        for (int t = 0; t < 2; t++)
            af[t] = *(const short8*)(As + (wm*32 + t*16 + ql) * 32 + akey);
#pragma unroll
        for (int t = 0; t < 2; t++)
#pragma unroll
            for (int u = 0; u < 4; u++)
                acc[t][u] = __builtin_amdgcn_mfma_f32_16x16x32_bf16(wf[u], af[t], acc[t][u], 0, 0, 0);
        __syncthreads();
    }
#pragma unroll
    for (int t = 0; t < 2; t++) {
        int m = m0 + wm*32 + t*16 + ql;
#pragma unroll
        for (int u = 0; u < 4; u++) {
            int n = n0 + wn*64 + u*16 + quad*4;
            float4 b4 = *(const float4*)(bias + n);
            float4 o;
            o.x = acc[t][u][0] + b4.x;
            o.y = acc[t][u][1] + b4.y;
            o.z = acc[t][u][2] + b4.z;
            o.w = acc[t][u][3] + b4.w;
            *(float4*)(out + (long)m * DIM + n) = o;
        }
    }
}

extern "C" void kernel_launch(void* const* d_in, const int* in_sizes, int n_in,
                              void* d_out, int out_size, void* d_ws, size_t ws_size,
                              hipStream_t stream) {
    const float* x  = (const float*)d_in[0];
    const float* y  = (const float*)d_in[1];
    const float* Wq = (const float*)d_in[2];
    const float* bq = (const float*)d_in[3];
    const float* Wk = (const float*)d_in[4];
    const float* bk = (const float*)d_in[5];
    const float* Wv = (const float*)d_in[6];
    const float* bv = (const float*)d_in[7];
    const float* Wo = (const float*)d_in[8];
    const float* bo = (const float*)d_in[9];
    float* out = (float*)d_out;

    const long NX = (long)ROWS * DIM;   // 2097152
    const long NW = (long)DIM * DIM;    // 65536
    unsigned short* xb   = (unsigned short*)d_ws;
    unsigned short* yb   = xb  + NX;
    unsigned short* Wqb  = yb  + NX;
    unsigned short* Wkb  = Wqb + NW;
    unsigned short* Wvb  = Wkb + NW;
    unsigned short* Wob  = Wvb + NW;
    unsigned short* qbf  = Wob + NW;
    unsigned short* kbf  = qbf + NX;
    unsigned short* vTb  = kbf + NX;
    unsigned short* attn = vTb + NX;    // ~24.5 MB total

    long total4 = (2*NX + 4*NW) / 4;    // 1114112
    convert_kernel<<<dim3((unsigned)((total4 + 255) / 256)), dim3(256), 0, stream>>>(
        x, y, Wq, Wk, Wv, Wo, xb, yb, Wqb, Wkb, Wvb, Wob);

    qkv_kernel<<<dim3(ROWS / 64, 2, 3), dim3(256), 0, stream>>>(
        xb, yb, Wqb, Wkb, Wvb, bq, bk, bv, qbf, kbf, vTb);

    attn_kernel<<<dim3(SEQ / 256, BATCH * NHEAD), dim3(256), 0, stream>>>(
        qbf, kbf, vTb, attn);

    oproj_kernel<<<dim3(ROWS / 64, 2), dim3(256), 0, stream>>>(
        attn, Wob, bo, out);
}

// Round 5
// 164.379 us; speedup vs baseline: 1.1573x; 1.1573x over previous
//
#include <hip/hip_runtime.h>

#define BATCH 2
#define SEQ   4096
#define DIM   256
#define NHEAD 8
#define HDIM  32
#define ROWS  (BATCH * SEQ)   // 8192

typedef __attribute__((ext_vector_type(8))) short short8;
typedef __attribute__((ext_vector_type(8))) unsigned short ushort8;
typedef __attribute__((ext_vector_type(4))) unsigned short ushortx4;
typedef __attribute__((ext_vector_type(4))) float floatx4;
typedef __attribute__((ext_vector_type(2))) unsigned int uintx2;

static __device__ __forceinline__ unsigned short f2bf(float f) {
    union { float f; unsigned u; } v; v.f = f;
    unsigned r = v.u + 0x7fffu + ((v.u >> 16) & 1u);   // RNE
    return (unsigned short)(r >> 16);
}
static __device__ __forceinline__ unsigned fbits(float f) {
    union { float f; unsigned u; } v; v.f = f; return v.u;
}
// pack two fp32 -> two bf16 (truncate) in ONE v_perm_b32
static __device__ __forceinline__ unsigned pack2(float a, float b) {
    return __builtin_amdgcn_perm(fbits(b), fbits(a), 0x07060302u);
}
// async global -> LDS: wave-uniform LDS base + lane*16
static __device__ __forceinline__ void g2l16(const void* g, void* l) {
    __builtin_amdgcn_global_load_lds(
        (const __attribute__((address_space(1))) unsigned int*)g,
        (__attribute__((address_space(3))) unsigned int*)l, 16, 0, 0);
}

// ---------------- fp32 -> bf16 conversion of the 4 weight matrices ----------
__global__ __launch_bounds__(256) void convw_kernel(
    const float* __restrict__ W0, const float* __restrict__ W1,
    const float* __restrict__ W2, const float* __restrict__ W3,
    unsigned short* __restrict__ o0, unsigned short* __restrict__ o1,
    unsigned short* __restrict__ o2, unsigned short* __restrict__ o3) {
    const float* s; unsigned short* d;
    switch (blockIdx.y) {
        case 0:  s = W0; d = o0; break;
        case 1:  s = W1; d = o1; break;
        case 2:  s = W2; d = o2; break;
        default: s = W3; d = o3; break;
    }
    long off = ((long)blockIdx.x * 256 + threadIdx.x) * 4;
    float4 v = *(const float4*)(s + off);
    ushortx4 o;
    o.x = f2bf(v.x); o.y = f2bf(v.y); o.z = f2bf(v.z); o.w = f2bf(v.w);
    *(ushortx4*)(d + off) = o;
}

// ---------------- fused QKV projection --------------------------------------
// grid (ROWS/64, 3): block = 64m x 256n, wave = 64m x 64n. ONE barrier total.
// mat 0: q = (x@Wq^T+bq)*scale (scale=(1/16)*log2 e); mat 1: k; mat 2: vT.
// x/y converted fp32->bf16 inline while staging to LDS (XOR-swizzled).
__global__ __launch_bounds__(256, 2) void qkv_kernel(
    const float* __restrict__ x, const float* __restrict__ y,
    const unsigned short* __restrict__ Wq, const unsigned short* __restrict__ Wk,
    const unsigned short* __restrict__ Wv,
    const float* __restrict__ bq, const float* __restrict__ bk, const float* __restrict__ bv,
    unsigned short* __restrict__ qo, unsigned short* __restrict__ ko,
    unsigned short* __restrict__ vto) {
    __shared__ unsigned short Abuf[8][64][32];
    const int tid = threadIdx.x, lane = tid & 63, wave = tid >> 6;
    const int ql = lane & 15, quad = lane >> 4;
    const int mat = blockIdx.y;
    const int m0 = blockIdx.x * 64;
    const float* A = (mat == 0) ? x : y;
    const unsigned short* W = (mat == 0) ? Wq : (mat == 1) ? Wk : Wv;
    const float* bias = (mat == 0) ? bq : (mat == 1) ? bk : bv;

    {   // stage full 64x256 A tile, fp32 -> bf16, chunk-XOR swizzle
        const int row = tid >> 2, c8 = (tid & 3) * 8;
        const int swz = ((tid & 3) ^ ((row >> 1) & 3)) * 8;
        const float* src = A + (long)(m0 + row) * DIM + c8;
#pragma unroll
        for (int kb = 0; kb < 8; kb++) {
            float4 v0 = *(const float4*)(src + kb * 32);
            float4 v1 = *(const float4*)(src + kb * 32 + 4);
            ushort8 o;
            o[0] = f2bf(v0.x); o[1] = f2bf(v0.y); o[2] = f2bf(v0.z); o[3] = f2bf(v0.w);
            o[4] = f2bf(v1.x); o[5] = f2bf(v1.y); o[6] = f2bf(v1.z); o[7] = f2bf(v1.w);
            *(ushort8*)(&Abuf[kb][row][swz]) = o;
        }
    }
    __syncthreads();
    const int n0 = wave * 64;
    const int akey = (quad ^ ((ql >> 1) & 3)) * 8;
    floatx4 acc[4][4] = {};
    for (int kb = 0; kb < 8; kb++) {
        short8 wf[4], af[4];
#pragma unroll
        for (int u = 0; u < 4; u++)
            wf[u] = *(const short8*)(W + (long)(n0 + u*16 + ql) * DIM + kb*32 + quad*8);
#pragma unroll
        for (int t = 0; t < 4; t++)
            af[t] = *(const short8*)(&Abuf[kb][t*16 + ql][akey]);
        if (mat < 2) {
#pragma unroll
            for (int t = 0; t < 4; t++)
#pragma unroll
                for (int u = 0; u < 4; u++)
                    acc[t][u] = __builtin_amdgcn_mfma_f32_16x16x32_bf16(wf[u], af[t], acc[t][u], 0, 0, 0);
        } else {
#pragma unroll
            for (int t = 0; t < 4; t++)
#pragma unroll
                for (int u = 0; u < 4; u++)
                    acc[t][u] = __builtin_amdgcn_mfma_f32_16x16x32_bf16(af[t], wf[u], acc[t][u], 0, 0, 0);
        }
    }
    if (mat < 2) {
        const float scale = (mat == 0) ? 0.09016844005556021f : 1.0f;
        unsigned short* out = (mat == 0) ? qo : ko;
#pragma unroll
        for (int t = 0; t < 4; t++) {
            int m = m0 + t*16 + ql;
#pragma unroll
            for (int u = 0; u < 4; u++) {
                int n = n0 + u*16 + quad*4;
                float4 b4 = *(const float4*)(bias + n);
                ushortx4 o;
                o.x = f2bf((acc[t][u][0] + b4.x) * scale);
                o.y = f2bf((acc[t][u][1] + b4.y) * scale);
                o.z = f2bf((acc[t][u][2] + b4.z) * scale);
                o.w = f2bf((acc[t][u][3] + b4.w) * scale);
                *(ushortx4*)(out + (long)m * DIM + n) = o;
            }
        }
    } else {
#pragma unroll
        for (int t = 0; t < 4; t++) {
            int mb = m0 + t*16 + quad*4;
            int bi = mb >> 12, i0 = mb & (SEQ - 1);
#pragma unroll
            for (int u = 0; u < 4; u++) {
                int n = n0 + u*16 + ql;
                float b = bias[n];
                ushortx4 o;
                o.x = f2bf(acc[t][u][0] + b);
                o.y = f2bf(acc[t][u][1] + b);
                o.z = f2bf(acc[t][u][2] + b);
                o.w = f2bf(acc[t][u][3] + b);
                *(ushortx4*)(vto + ((long)(bi * DIM + n)) * SEQ + i0) = o;
            }
        }
    }
}

// ---------------- attention: 128-q blocks, 32 q/wave, kv-tile 64 dbuf -------
// LDS 34.4 KB -> 4 blocks/CU (16 waves/CU) via __launch_bounds__(256,4).
// Swizzled K/V staging (verified R4), per-wave P round-trip, exp2 softmax
// without max subtraction, l via ones-MFMA.
__global__ __launch_bounds__(256, 4) void attn_kernel(
    const unsigned short* __restrict__ qb, const unsigned short* __restrict__ kbuf,
    const unsigned short* __restrict__ vT, unsigned short* __restrict__ ao) {
    __shared__ unsigned short K0[64 * 32], K1[64 * 32];
    __shared__ unsigned short V0[32 * 64], V1[32 * 64];
    __shared__ unsigned short P[4][32][72];
    const int tid = threadIdx.x, lane = tid & 63, wave = tid >> 6;
    const int ql = lane & 15, quad = lane >> 4;
    const int bh = blockIdx.y, b = bh >> 3, h = bh & 7;
    const int q0 = blockIdx.x * 128 + wave * 32;

    const unsigned short* qrow = qb   + (long)b * SEQ * DIM + h * HDIM;
    const unsigned short* krow = kbuf + (long)b * SEQ * DIM + h * HDIM;
    const unsigned short* vrow = vT   + (long)(b * DIM + h * HDIM) * SEQ;

    short8 qf[2];
#pragma unroll
    for (int t = 0; t < 2; t++)
        qf[t] = *(const short8*)(qrow + (long)(q0 + t*16 + ql) * DIM + quad*8);

    short8 ones;
#pragma unroll
    for (int i = 0; i < 8; i++) ones[i] = (short)0x3F80;

    // staging: wave stages K rows [16w,16w+16) (64B rows, 4 chunks) and
    // V rows [8w,8w+8) (128B rows, 8 chunks), chunk-XOR swizzled.
    const unsigned short* kg = krow + (long)(wave*16 + (lane >> 2)) * DIM
                                    + ((lane & 3) ^ ((lane >> 3) & 3)) * 8;
    const unsigned short* vg = vrow + (long)(wave*8 + (lane >> 3)) * SEQ
                                    + ((lane & 7) ^ (lane >> 3)) * 8;
    unsigned short* kd0 = K0 + wave * 512;  unsigned short* kd1 = K1 + wave * 512;
    unsigned short* vd0 = V0 + wave * 512;  unsigned short* vd1 = V1 + wave * 512;
    const int kro = (quad ^ ((ql >> 1) & 3)) * 8;   // K read chunk pos
    const int vmask = ql & 7;                        // V read xor key

    floatx4 acc[2][2] = {};    // O^T accum [dim-tile][q-tile]
    floatx4 accL[2] = {};      // row-sums via ones-MFMA

    auto compute = [&](const unsigned short* Ks, const unsigned short* Vs) {
#pragma unroll
        for (int mt = 0; mt < 4; ++mt) {
            short8 kf = *(const short8*)(Ks + (mt*16 + ql) * 32 + kro);
#pragma unroll
            for (int t = 0; t < 2; t++) {
                floatx4 z = {};
                floatx4 s = __builtin_amdgcn_mfma_f32_16x16x32_bf16(kf, qf[t], z, 0, 0, 0);
                float p0 = __builtin_amdgcn_exp2f(s[0]);
                float p1 = __builtin_amdgcn_exp2f(s[1]);
                float p2 = __builtin_amdgcn_exp2f(s[2]);
                float p3 = __builtin_amdgcn_exp2f(s[3]);
                uintx2 w;
                w.x = pack2(p0, p1);
                w.y = pack2(p2, p3);
                *(uintx2*)(&P[wave][t*16 + ql][mt*16 + quad*4]) = w;
            }
        }
#pragma unroll
        for (int ks = 0; ks < 2; ++ks) {
            short8 pf[2];
#pragma unroll
            for (int t = 0; t < 2; t++)
                pf[t] = *(const short8*)(&P[wave][t*16 + ql][ks*32 + quad*8]);
#pragma unroll
            for (int t = 0; t < 2; t++)
                accL[t] = __builtin_amdgcn_mfma_f32_16x16x32_bf16(ones, pf[t], accL[t], 0, 0, 0);
#pragma unroll
            for (int dt = 0; dt < 2; ++dt) {
                short8 vf = *(const short8*)(Vs + (dt*16 + ql) * 64 + ((ks*4 + quad) ^ vmask) * 8);
#pragma unroll
                for (int t = 0; t < 2; t++)
                    acc[dt][t] = __builtin_amdgcn_mfma_f32_16x16x32_bf16(vf, pf[t], acc[dt][t], 0, 0, 0);
            }
        }
    };

    g2l16(kg, kd0); g2l16(vg, vd0);
    __syncthreads();
    for (int it = 0; it < SEQ / 64; it += 2) {
        if (it + 1 < SEQ / 64) {
            g2l16(kg + (long)(it + 1) * 64 * DIM, kd1);
            g2l16(vg + (it + 1) * 64, vd1);
        }
        compute(K0, V0);
        __syncthreads();
        if (it + 2 < SEQ / 64) {
            g2l16(kg + (long)(it + 2) * 64 * DIM, kd0);
            g2l16(vg + (it + 2) * 64, vd0);
        }
        compute(K1, V1);
        __syncthreads();
    }

    float inv[2];
#pragma unroll
    for (int t = 0; t < 2; t++) inv[t] = 1.0f / accL[t][0];
#pragma unroll
    for (int dt = 0; dt < 2; dt++)
#pragma unroll
        for (int t = 0; t < 2; t++) {
            ushortx4 o;
            o.x = f2bf(acc[dt][t][0] * inv[t]);
            o.y = f2bf(acc[dt][t][1] * inv[t]);
            o.z = f2bf(acc[dt][t][2] * inv[t]);
            o.w = f2bf(acc[dt][t][3] * inv[t]);
            *(ushortx4*)(ao + (long)(b*SEQ + q0 + t*16 + ql) * DIM + h*HDIM + dt*16 + quad*4) = o;
        }
}

// ---------------- output projection: fp32 out, 64m x 256n, ONE barrier ------
__global__ __launch_bounds__(256, 2) void oproj_kernel(
    const unsigned short* __restrict__ A, const unsigned short* __restrict__ W,
    const float* __restrict__ bias, float* __restrict__ out) {
    __shared__ unsigned short Abuf[8][64][32];
    const int tid = threadIdx.x, lane = tid & 63, wave = tid >> 6;
    const int ql = lane & 15, quad = lane >> 4;
    const int m0 = blockIdx.x * 64;
    // stage 64x256 bf16 A tile via g2l16 (8 chunks/wave), chunk-XOR swizzled
    const int swz = ((lane & 3) ^ ((lane >> 3) & 3)) * 8;
#pragma unroll
    for (int j = 0; j < 8; j++) {
        int c = wave * 8 + j;
        int kb = c >> 2, r0 = (c & 3) * 16;
        const unsigned short* g = A + (long)(m0 + r0 + (lane >> 2)) * DIM + kb*32 + swz;
        g2l16(g, &Abuf[kb][r0][0]);
    }
    __syncthreads();
    const int n0 = wave * 64;
    const int akey = (quad ^ ((ql >> 1) & 3)) * 8;
    floatx4 acc[4][4] = {};
    for (int kb = 0; kb < 8; kb++) {
        short8 wf[4], af[4];
#pragma unroll
        for (int u = 0; u < 4; u++)
            wf[u] = *(const short8*)(W + (long)(n0 + u*16 + ql) * DIM + kb*32 + quad*8);
#pragma unroll
        for (int t = 0; t < 4; t++)
            af[t] = *(const short8*)(&Abuf[kb][t*16 + ql][akey]);
#pragma unroll
        for (int t = 0; t < 4; t++)
#pragma unroll
            for (int u = 0; u < 4; u++)
                acc[t][u] = __builtin_amdgcn_mfma_f32_16x16x32_bf16(wf[u], af[t], acc[t][u], 0, 0, 0);
    }
#pragma unroll
    for (int t = 0; t < 4; t++) {
        int m = m0 + t*16 + ql;
#pragma unroll
        for (int u = 0; u < 4; u++) {
            int n = n0 + u*16 + quad*4;
            float4 b4 = *(const float4*)(bias + n);
            float4 o;
            o.x = acc[t][u][0] + b4.x;
            o.y = acc[t][u][1] + b4.y;
            o.z = acc[t][u][2] + b4.z;
            o.w = acc[t][u][3] + b4.w;
            *(float4*)(out + (long)m * DIM + n) = o;
        }
    }
}

extern "C" void kernel_launch(void* const* d_in, const int* in_sizes, int n_in,
                              void* d_out, int out_size, void* d_ws, size_t ws_size,
                              hipStream_t stream) {
    const float* x  = (const float*)d_in[0];
    const float* y  = (const float*)d_in[1];
    const float* Wq = (const float*)d_in[2];
    const float* bq = (const float*)d_in[3];
    const float* Wk = (const float*)d_in[4];
    const float* bk = (const float*)d_in[5];
    const float* Wv = (const float*)d_in[6];
    const float* bv = (const float*)d_in[7];
    const float* Wo = (const float*)d_in[8];
    const float* bo = (const float*)d_in[9];
    float* out = (float*)d_out;

    const long NX = (long)ROWS * DIM;   // 2097152
    const long NW = (long)DIM * DIM;    // 65536
    unsigned short* Wqb  = (unsigned short*)d_ws;
    unsigned short* Wkb  = Wqb + NW;
    unsigned short* Wvb  = Wkb + NW;
    unsigned short* Wob  = Wvb + NW;
    unsigned short* qbf  = Wob + NW;
    unsigned short* kbf  = qbf + NX;
    unsigned short* vTb  = kbf + NX;
    unsigned short* attn = vTb + NX;    // ~16.5 MB total

    convw_kernel<<<dim3(NW / 1024, 4), dim3(256), 0, stream>>>(
        Wq, Wk, Wv, Wo, Wqb, Wkb, Wvb, Wob);

    qkv_kernel<<<dim3(ROWS / 64, 3), dim3(256), 0, stream>>>(
        x, y, Wqb, Wkb, Wvb, bq, bk, bv, qbf, kbf, vTb);

    attn_kernel<<<dim3(SEQ / 128, BATCH * NHEAD), dim3(256), 0, stream>>>(
        qbf, kbf, vTb, attn);

    oproj_kernel<<<dim3(ROWS / 64), dim3(256), 0, stream>>>(
        attn, Wob, bo, out);
}

// Round 6
// 159.921 us; speedup vs baseline: 1.1895x; 1.0279x over previous
//
#include <hip/hip_runtime.h>

#define BATCH 2
#define SEQ   4096
#define DIM   256
#define NHEAD 8
#define HDIM  32
#define ROWS  (BATCH * SEQ)   // 8192

typedef __attribute__((ext_vector_type(8))) short short8;
typedef __attribute__((ext_vector_type(8))) unsigned short ushort8;
typedef __attribute__((ext_vector_type(4))) unsigned short ushortx4;
typedef __attribute__((ext_vector_type(4))) float floatx4;
typedef __attribute__((ext_vector_type(2))) unsigned int uintx2;
typedef __attribute__((ext_vector_type(4))) unsigned int uintx4;

static __device__ __forceinline__ unsigned short f2bf(float f) {
    union { float f; unsigned u; } v; v.f = f;
    unsigned r = v.u + 0x7fffu + ((v.u >> 16) & 1u);   // RNE
    return (unsigned short)(r >> 16);
}
static __device__ __forceinline__ unsigned fbits(float f) {
    union { float f; unsigned u; } v; v.f = f; return v.u;
}
// pack two fp32 -> two bf16 (truncate) in ONE v_perm_b32
static __device__ __forceinline__ unsigned pack2(float a, float b) {
    return __builtin_amdgcn_perm(fbits(b), fbits(a), 0x07060302u);
}
// async global -> LDS: wave-uniform LDS base + lane*16
static __device__ __forceinline__ void g2l16(const void* g, void* l) {
    __builtin_amdgcn_global_load_lds(
        (const __attribute__((address_space(1))) unsigned int*)g,
        (__attribute__((address_space(3))) unsigned int*)l, 16, 0, 0);
}

#if __has_builtin(__builtin_amdgcn_permlane32_swap) && __has_builtin(__builtin_amdgcn_permlane16_swap)
#define HAVE_PLSWAP 1
#else
#define HAVE_PLSWAP 0
#endif

// ---------------- fp32 -> bf16 conversion of the 4 weight matrices ----------
__global__ __launch_bounds__(256) void convw_kernel(
    const float* __restrict__ W0, const float* __restrict__ W1,
    const float* __restrict__ W2, const float* __restrict__ W3,
    unsigned short* __restrict__ o0, unsigned short* __restrict__ o1,
    unsigned short* __restrict__ o2, unsigned short* __restrict__ o3) {
    const float* s; unsigned short* d;
    switch (blockIdx.y) {
        case 0:  s = W0; d = o0; break;
        case 1:  s = W1; d = o1; break;
        case 2:  s = W2; d = o2; break;
        default: s = W3; d = o3; break;
    }
    long off = ((long)blockIdx.x * 256 + threadIdx.x) * 4;
    float4 v = *(const float4*)(s + off);
    ushortx4 o;
    o.x = f2bf(v.x); o.y = f2bf(v.y); o.z = f2bf(v.z); o.w = f2bf(v.w);
    *(ushortx4*)(d + off) = o;
}

// ---------------- fused QKV projection (unchanged from R5) ------------------
__global__ __launch_bounds__(256, 2) void qkv_kernel(
    const float* __restrict__ x, const float* __restrict__ y,
    const unsigned short* __restrict__ Wq, const unsigned short* __restrict__ Wk,
    const unsigned short* __restrict__ Wv,
    const float* __restrict__ bq, const float* __restrict__ bk, const float* __restrict__ bv,
    unsigned short* __restrict__ qo, unsigned short* __restrict__ ko,
    unsigned short* __restrict__ vto) {
    __shared__ unsigned short Abuf[8][64][32];
    const int tid = threadIdx.x, lane = tid & 63, wave = tid >> 6;
    const int ql = lane & 15, quad = lane >> 4;
    const int mat = blockIdx.y;
    const int m0 = blockIdx.x * 64;
    const float* A = (mat == 0) ? x : y;
    const unsigned short* W = (mat == 0) ? Wq : (mat == 1) ? Wk : Wv;
    const float* bias = (mat == 0) ? bq : (mat == 1) ? bk : bv;

    {   // stage full 64x256 A tile, fp32 -> bf16, chunk-XOR swizzle
        const int row = tid >> 2, c8 = (tid & 3) * 8;
        const int swz = ((tid & 3) ^ ((row >> 1) & 3)) * 8;
        const float* src = A + (long)(m0 + row) * DIM + c8;
#pragma unroll
        for (int kb = 0; kb < 8; kb++) {
            float4 v0 = *(const float4*)(src + kb * 32);
            float4 v1 = *(const float4*)(src + kb * 32 + 4);
            ushort8 o;
            o[0] = f2bf(v0.x); o[1] = f2bf(v0.y); o[2] = f2bf(v0.z); o[3] = f2bf(v0.w);
            o[4] = f2bf(v1.x); o[5] = f2bf(v1.y); o[6] = f2bf(v1.z); o[7] = f2bf(v1.w);
            *(ushort8*)(&Abuf[kb][row][swz]) = o;
        }
    }
    __syncthreads();
    const int n0 = wave * 64;
    const int akey = (quad ^ ((ql >> 1) & 3)) * 8;
    floatx4 acc[4][4] = {};
    for (int kb = 0; kb < 8; kb++) {
        short8 wf[4], af[4];
#pragma unroll
        for (int u = 0; u < 4; u++)
            wf[u] = *(const short8*)(W + (long)(n0 + u*16 + ql) * DIM + kb*32 + quad*8);
#pragma unroll
        for (int t = 0; t < 4; t++)
            af[t] = *(const short8*)(&Abuf[kb][t*16 + ql][akey]);
        if (mat < 2) {
#pragma unroll
            for (int t = 0; t < 4; t++)
#pragma unroll
                for (int u = 0; u < 4; u++)
                    acc[t][u] = __builtin_amdgcn_mfma_f32_16x16x32_bf16(wf[u], af[t], acc[t][u], 0, 0, 0);
        } else {
#pragma unroll
            for (int t = 0; t < 4; t++)
#pragma unroll
                for (int u = 0; u < 4; u++)
                    acc[t][u] = __builtin_amdgcn_mfma_f32_16x16x32_bf16(af[t], wf[u], acc[t][u], 0, 0, 0);
        }
    }
    if (mat < 2) {
        const float scale = (mat == 0) ? 0.09016844005556021f : 1.0f;
        unsigned short* out = (mat == 0) ? qo : ko;
#pragma unroll
        for (int t = 0; t < 4; t++) {
            int m = m0 + t*16 + ql;
#pragma unroll
            for (int u = 0; u < 4; u++) {
                int n = n0 + u*16 + quad*4;
                float4 b4 = *(const float4*)(bias + n);
                ushortx4 o;
                o.x = f2bf((acc[t][u][0] + b4.x) * scale);
                o.y = f2bf((acc[t][u][1] + b4.y) * scale);
                o.z = f2bf((acc[t][u][2] + b4.z) * scale);
                o.w = f2bf((acc[t][u][3] + b4.w) * scale);
                *(ushortx4*)(out + (long)m * DIM + n) = o;
            }
        }
    } else {
#pragma unroll
        for (int t = 0; t < 4; t++) {
            int mb = m0 + t*16 + quad*4;
            int bi = mb >> 12, i0 = mb & (SEQ - 1);
#pragma unroll
            for (int u = 0; u < 4; u++) {
                int n = n0 + u*16 + ql;
                float b = bias[n];
                ushortx4 o;
                o.x = f2bf(acc[t][u][0] + b);
                o.y = f2bf(acc[t][u][1] + b);
                o.z = f2bf(acc[t][u][2] + b);
                o.w = f2bf(acc[t][u][3] + b);
                *(ushortx4*)(vto + ((long)(bi * DIM + n)) * SEQ + i0) = o;
            }
        }
    }
}

// ---------------- attention: P transposed IN REGISTERS via permlane swaps ---
// Sᵀ C-frag (lane: q=ql, kv=16mt+4quad+reg, packed as 2 b32 per mt) is turned
// into the PV B-frag (lane: q=ql, kv=8quad+j) by one permlane32_swap + one
// permlane16_swap per register pair: (r0,r2)=pl16(pl32(a0,a2)); (r1,r3)=same(a1,a3).
// Eliminates the entire P LDS round-trip (4 B/unit of LDS traffic).
__global__ __launch_bounds__(256, 4) void attn_kernel(
    const unsigned short* __restrict__ qb, const unsigned short* __restrict__ kbuf,
    const unsigned short* __restrict__ vT, unsigned short* __restrict__ ao) {
    __shared__ unsigned short K0[64 * 32], K1[64 * 32];
    __shared__ unsigned short V0[32 * 64], V1[32 * 64];
#if !HAVE_PLSWAP
    __shared__ unsigned short P[4][32][72];
#endif
    const int tid = threadIdx.x, lane = tid & 63, wave = tid >> 6;
    const int ql = lane & 15, quad = lane >> 4;
    const int bh = blockIdx.y, b = bh >> 3, h = bh & 7;
    const int q0 = blockIdx.x * 128 + wave * 32;

    const unsigned short* qrow = qb   + (long)b * SEQ * DIM + h * HDIM;
    const unsigned short* krow = kbuf + (long)b * SEQ * DIM + h * HDIM;
    const unsigned short* vrow = vT   + (long)(b * DIM + h * HDIM) * SEQ;

    short8 qf[2];
#pragma unroll
    for (int t = 0; t < 2; t++)
        qf[t] = *(const short8*)(qrow + (long)(q0 + t*16 + ql) * DIM + quad*8);

    short8 ones;
#pragma unroll
    for (int i = 0; i < 8; i++) ones[i] = (short)0x3F80;

    const unsigned short* kg = krow + (long)(wave*16 + (lane >> 2)) * DIM
                                    + ((lane & 3) ^ ((lane >> 3) & 3)) * 8;
    const unsigned short* vg = vrow + (long)(wave*8 + (lane >> 3)) * SEQ
                                    + ((lane & 7) ^ (lane >> 3)) * 8;
    unsigned short* kd0 = K0 + wave * 512;  unsigned short* kd1 = K1 + wave * 512;
    unsigned short* vd0 = V0 + wave * 512;  unsigned short* vd1 = V1 + wave * 512;
    const int kro = (quad ^ ((ql >> 1) & 3)) * 8;   // K read chunk pos
    const int vmask = ql & 7;                        // V read xor key

    floatx4 acc[2][2] = {};    // Oᵀ accum [dim-tile][q-tile]
    floatx4 accL[2] = {};      // row-sums via ones-MFMA

    auto compute = [&](const unsigned short* Ks, const unsigned short* Vs) {
        unsigned pk[4][2][2];   // [mt][t][b32]: packed exp2(S) in C-layout
#pragma unroll
        for (int mt = 0; mt < 4; ++mt) {
            short8 kf = *(const short8*)(Ks + (mt*16 + ql) * 32 + kro);
#pragma unroll
            for (int t = 0; t < 2; t++) {
                floatx4 z = {};
                floatx4 s = __builtin_amdgcn_mfma_f32_16x16x32_bf16(kf, qf[t], z, 0, 0, 0);
                float p0 = __builtin_amdgcn_exp2f(s[0]);
                float p1 = __builtin_amdgcn_exp2f(s[1]);
                float p2 = __builtin_amdgcn_exp2f(s[2]);
                float p3 = __builtin_amdgcn_exp2f(s[3]);
                pk[mt][t][0] = pack2(p0, p1);
                pk[mt][t][1] = pack2(p2, p3);
#if !HAVE_PLSWAP
                uintx2 w; w.x = pk[mt][t][0]; w.y = pk[mt][t][1];
                *(uintx2*)(&P[wave][t*16 + ql][mt*16 + quad*4]) = w;
#endif
            }
        }
#pragma unroll
        for (int ks = 0; ks < 2; ++ks) {
            short8 pf[2];
#pragma unroll
            for (int t = 0; t < 2; t++) {
#if HAVE_PLSWAP
                // in-register C->B transpose
                uintx2 x0 = __builtin_amdgcn_permlane32_swap(pk[2*ks][t][0], pk[2*ks+1][t][0], false, false);
                uintx2 y0 = __builtin_amdgcn_permlane16_swap(x0.x, x0.y, false, false);   // {r0, r2}
                uintx2 x1 = __builtin_amdgcn_permlane32_swap(pk[2*ks][t][1], pk[2*ks+1][t][1], false, false);
                uintx2 y1 = __builtin_amdgcn_permlane16_swap(x1.x, x1.y, false, false);   // {r1, r3}
                uintx4 pv; pv.x = y0.x; pv.y = y1.x; pv.z = y0.y; pv.w = y1.y;
                pf[t] = *(short8*)&pv;
#else
                pf[t] = *(const short8*)(&P[wave][t*16 + ql][ks*32 + quad*8]);
#endif
            }
#pragma unroll
            for (int t = 0; t < 2; t++)
                accL[t] = __builtin_amdgcn_mfma_f32_16x16x32_bf16(ones, pf[t], accL[t], 0, 0, 0);
#pragma unroll
            for (int dt = 0; dt < 2; ++dt) {
                short8 vf = *(const short8*)(Vs + (dt*16 + ql) * 64 + ((ks*4 + quad) ^ vmask) * 8);
#pragma unroll
                for (int t = 0; t < 2; t++)
                    acc[dt][t] = __builtin_amdgcn_mfma_f32_16x16x32_bf16(vf, pf[t], acc[dt][t], 0, 0, 0);
            }
        }
    };

    g2l16(kg, kd0); g2l16(vg, vd0);
    __syncthreads();
    for (int it = 0; it < SEQ / 64; it += 2) {
        if (it + 1 < SEQ / 64) {
            g2l16(kg + (long)(it + 1) * 64 * DIM, kd1);
            g2l16(vg + (it + 1) * 64, vd1);
        }
        compute(K0, V0);
        __syncthreads();
        if (it + 2 < SEQ / 64) {
            g2l16(kg + (long)(it + 2) * 64 * DIM, kd0);
            g2l16(vg + (it + 2) * 64, vd0);
        }
        compute(K1, V1);
        __syncthreads();
    }

    float inv[2];
#pragma unroll
    for (int t = 0; t < 2; t++) inv[t] = 1.0f / accL[t][0];
#pragma unroll
    for (int dt = 0; dt < 2; dt++)
#pragma unroll
        for (int t = 0; t < 2; t++) {
            ushortx4 o;
            o.x = f2bf(acc[dt][t][0] * inv[t]);
            o.y = f2bf(acc[dt][t][1] * inv[t]);
            o.z = f2bf(acc[dt][t][2] * inv[t]);
            o.w = f2bf(acc[dt][t][3] * inv[t]);
            *(ushortx4*)(ao + (long)(b*SEQ + q0 + t*16 + ql) * DIM + h*HDIM + dt*16 + quad*4) = o;
        }
}

// ---------------- output projection (unchanged from R5) ---------------------
__global__ __launch_bounds__(256, 2) void oproj_kernel(
    const unsigned short* __restrict__ A, const unsigned short* __restrict__ W,
    const float* __restrict__ bias, float* __restrict__ out) {
    __shared__ unsigned short Abuf[8][64][32];
    const int tid = threadIdx.x, lane = tid & 63, wave = tid >> 6;
    const int ql = lane & 15, quad = lane >> 4;
    const int m0 = blockIdx.x * 64;
    const int swz = ((lane & 3) ^ ((lane >> 3) & 3)) * 8;
#pragma unroll
    for (int j = 0; j < 8; j++) {
        int c = wave * 8 + j;
        int kb = c >> 2, r0 = (c & 3) * 16;
        const unsigned short* g = A + (long)(m0 + r0 + (lane >> 2)) * DIM + kb*32 + swz;
        g2l16(g, &Abuf[kb][r0][0]);
    }
    __syncthreads();
    const int n0 = wave * 64;
    const int akey = (quad ^ ((ql >> 1) & 3)) * 8;
    floatx4 acc[4][4] = {};
    for (int kb = 0; kb < 8; kb++) {
        short8 wf[4], af[4];
#pragma unroll
        for (int u = 0; u < 4; u++)
            wf[u] = *(const short8*)(W + (long)(n0 + u*16 + ql) * DIM + kb*32 + quad*8);
#pragma unroll
        for (int t = 0; t < 4; t++)
            af[t] = *(const short8*)(&Abuf[kb][t*16 + ql][akey]);
#pragma unroll
        for (int t = 0; t < 4; t++)
#pragma unroll
            for (int u = 0; u < 4; u++)
                acc[t][u] = __builtin_amdgcn_mfma_f32_16x16x32_bf16(wf[u], af[t], acc[t][u], 0, 0, 0);
    }
#pragma unroll
    for (int t = 0; t < 4; t++) {
        int m = m0 + t*16 + ql;
#pragma unroll
        for (int u = 0; u < 4; u++) {
            int n = n0 + u*16 + quad*4;
            float4 b4 = *(const float4*)(bias + n);
            float4 o;
            o.x = acc[t][u][0] + b4.x;
            o.y = acc[t][u][1] + b4.y;
            o.z = acc[t][u][2] + b4.z;
            o.w = acc[t][u][3] + b4.w;
            *(float4*)(out + (long)m * DIM + n) = o;
        }
    }
}

extern "C" void kernel_launch(void* const* d_in, const int* in_sizes, int n_in,
                              void* d_out, int out_size, void* d_ws, size_t ws_size,
                              hipStream_t stream) {
    const float* x  = (const float*)d_in[0];
    const float* y  = (const float*)d_in[1];
    const float* Wq = (const float*)d_in[2];
    const float* bq = (const float*)d_in[3];
    const float* Wk = (const float*)d_in[4];
    const float* bk = (const float*)d_in[5];
    const float* Wv = (const float*)d_in[6];
    const float* bv = (const float*)d_in[7];
    const float* Wo = (const float*)d_in[8];
    const float* bo = (const float*)d_in[9];
    float* out = (float*)d_out;

    const long NX = (long)ROWS * DIM;   // 2097152
    const long NW = (long)DIM * DIM;    // 65536
    unsigned short* Wqb  = (unsigned short*)d_ws;
    unsigned short* Wkb  = Wqb + NW;
    unsigned short* Wvb  = Wkb + NW;
    unsigned short* Wob  = Wvb + NW;
    unsigned short* qbf  = Wob + NW;
    unsigned short* kbf  = qbf + NX;
    unsigned short* vTb  = kbf + NX;
    unsigned short* attn = vTb + NX;    // ~16.5 MB total

    convw_kernel<<<dim3(NW / 1024, 4), dim3(256), 0, stream>>>(
        Wq, Wk, Wv, Wo, Wqb, Wkb, Wvb, Wob);

    qkv_kernel<<<dim3(ROWS / 64, 3), dim3(256), 0, stream>>>(
        x, y, Wqb, Wkb, Wvb, bq, bk, bv, qbf, kbf, vTb);

    attn_kernel<<<dim3(SEQ / 128, BATCH * NHEAD), dim3(256), 0, stream>>>(
        qbf, kbf, vTb, attn);

    oproj_kernel<<<dim3(ROWS / 64), dim3(256), 0, stream>>>(
        attn, Wob, bo, out);
}

// Round 7
// 159.109 us; speedup vs baseline: 1.1956x; 1.0051x over previous
//
#include <hip/hip_runtime.h>

#define BATCH 2
#define SEQ   4096
#define DIM   256
#define NHEAD 8
#define HDIM  32
#define ROWS  (BATCH * SEQ)   // 8192

typedef __attribute__((ext_vector_type(8))) short short8;
typedef __attribute__((ext_vector_type(8))) unsigned short ushort8;
typedef __attribute__((ext_vector_type(4))) unsigned short ushortx4;
typedef __attribute__((ext_vector_type(4))) float floatx4;
typedef __attribute__((ext_vector_type(2))) unsigned int uintx2;
typedef __attribute__((ext_vector_type(4))) unsigned int uintx4;

static __device__ __forceinline__ unsigned short f2bf(float f) {
    union { float f; unsigned u; } v; v.f = f;
    unsigned r = v.u + 0x7fffu + ((v.u >> 16) & 1u);   // RNE
    return (unsigned short)(r >> 16);
}
static __device__ __forceinline__ unsigned fbits(float f) {
    union { float f; unsigned u; } v; v.f = f; return v.u;
}
// pack two fp32 -> two bf16 (truncate) in ONE v_perm_b32
static __device__ __forceinline__ unsigned pack2(float a, float b) {
    return __builtin_amdgcn_perm(fbits(b), fbits(a), 0x07060302u);
}
// async global -> LDS: wave-uniform LDS base + lane*16
static __device__ __forceinline__ void g2l16(const void* g, void* l) {
    __builtin_amdgcn_global_load_lds(
        (const __attribute__((address_space(1))) unsigned int*)g,
        (__attribute__((address_space(3))) unsigned int*)l, 16, 0, 0);
}

#if __has_builtin(__builtin_amdgcn_permlane32_swap) && __has_builtin(__builtin_amdgcn_permlane16_swap)
#define HAVE_PLSWAP 1
#else
#define HAVE_PLSWAP 0
#endif

// ---------------- fp32 -> bf16 conversion of the 4 weight matrices ----------
__global__ __launch_bounds__(256) void convw_kernel(
    const float* __restrict__ W0, const float* __restrict__ W1,
    const float* __restrict__ W2, const float* __restrict__ W3,
    unsigned short* __restrict__ o0, unsigned short* __restrict__ o1,
    unsigned short* __restrict__ o2, unsigned short* __restrict__ o3) {
    const float* s; unsigned short* d;
    switch (blockIdx.y) {
        case 0:  s = W0; d = o0; break;
        case 1:  s = W1; d = o1; break;
        case 2:  s = W2; d = o2; break;
        default: s = W3; d = o3; break;
    }
    long off = ((long)blockIdx.x * 256 + threadIdx.x) * 4;
    float4 v = *(const float4*)(s + off);
    ushortx4 o;
    o.x = f2bf(v.x); o.y = f2bf(v.y); o.z = f2bf(v.z); o.w = f2bf(v.w);
    *(ushortx4*)(d + off) = o;
}

// ---------------- fused QKV projection (unchanged from R6) ------------------
__global__ __launch_bounds__(256, 2) void qkv_kernel(
    const float* __restrict__ x, const float* __restrict__ y,
    const unsigned short* __restrict__ Wq, const unsigned short* __restrict__ Wk,
    const unsigned short* __restrict__ Wv,
    const float* __restrict__ bq, const float* __restrict__ bk, const float* __restrict__ bv,
    unsigned short* __restrict__ qo, unsigned short* __restrict__ ko,
    unsigned short* __restrict__ vto) {
    __shared__ unsigned short Abuf[8][64][32];
    const int tid = threadIdx.x, lane = tid & 63, wave = tid >> 6;
    const int ql = lane & 15, quad = lane >> 4;
    const int mat = blockIdx.y;
    const int m0 = blockIdx.x * 64;
    const float* A = (mat == 0) ? x : y;
    const unsigned short* W = (mat == 0) ? Wq : (mat == 1) ? Wk : Wv;
    const float* bias = (mat == 0) ? bq : (mat == 1) ? bk : bv;

    {   // stage full 64x256 A tile, fp32 -> bf16, chunk-XOR swizzle
        const int row = tid >> 2, c8 = (tid & 3) * 8;
        const int swz = ((tid & 3) ^ ((row >> 1) & 3)) * 8;
        const float* src = A + (long)(m0 + row) * DIM + c8;
#pragma unroll
        for (int kb = 0; kb < 8; kb++) {
            float4 v0 = *(const float4*)(src + kb * 32);
            float4 v1 = *(const float4*)(src + kb * 32 + 4);
            ushort8 o;
            o[0] = f2bf(v0.x); o[1] = f2bf(v0.y); o[2] = f2bf(v0.z); o[3] = f2bf(v0.w);
            o[4] = f2bf(v1.x); o[5] = f2bf(v1.y); o[6] = f2bf(v1.z); o[7] = f2bf(v1.w);
            *(ushort8*)(&Abuf[kb][row][swz]) = o;
        }
    }
    __syncthreads();
    const int n0 = wave * 64;
    const int akey = (quad ^ ((ql >> 1) & 3)) * 8;
    floatx4 acc[4][4] = {};
    for (int kb = 0; kb < 8; kb++) {
        short8 wf[4], af[4];
#pragma unroll
        for (int u = 0; u < 4; u++)
            wf[u] = *(const short8*)(W + (long)(n0 + u*16 + ql) * DIM + kb*32 + quad*8);
#pragma unroll
        for (int t = 0; t < 4; t++)
            af[t] = *(const short8*)(&Abuf[kb][t*16 + ql][akey]);
        if (mat < 2) {
#pragma unroll
            for (int t = 0; t < 4; t++)
#pragma unroll
                for (int u = 0; u < 4; u++)
                    acc[t][u] = __builtin_amdgcn_mfma_f32_16x16x32_bf16(wf[u], af[t], acc[t][u], 0, 0, 0);
        } else {
#pragma unroll
            for (int t = 0; t < 4; t++)
#pragma unroll
                for (int u = 0; u < 4; u++)
                    acc[t][u] = __builtin_amdgcn_mfma_f32_16x16x32_bf16(af[t], wf[u], acc[t][u], 0, 0, 0);
        }
    }
    if (mat < 2) {
        const float scale = (mat == 0) ? 0.09016844005556021f : 1.0f;
        unsigned short* out = (mat == 0) ? qo : ko;
#pragma unroll
        for (int t = 0; t < 4; t++) {
            int m = m0 + t*16 + ql;
#pragma unroll
            for (int u = 0; u < 4; u++) {
                int n = n0 + u*16 + quad*4;
                float4 b4 = *(const float4*)(bias + n);
                ushortx4 o;
                o.x = f2bf((acc[t][u][0] + b4.x) * scale);
                o.y = f2bf((acc[t][u][1] + b4.y) * scale);
                o.z = f2bf((acc[t][u][2] + b4.z) * scale);
                o.w = f2bf((acc[t][u][3] + b4.w) * scale);
                *(ushortx4*)(out + (long)m * DIM + n) = o;
            }
        }
    } else {
#pragma unroll
        for (int t = 0; t < 4; t++) {
            int mb = m0 + t*16 + quad*4;
            int bi = mb >> 12, i0 = mb & (SEQ - 1);
#pragma unroll
            for (int u = 0; u < 4; u++) {
                int n = n0 + u*16 + ql;
                float b = bias[n];
                ushortx4 o;
                o.x = f2bf(acc[t][u][0] + b);
                o.y = f2bf(acc[t][u][1] + b);
                o.z = f2bf(acc[t][u][2] + b);
                o.w = f2bf(acc[t][u][3] + b);
                *(ushortx4*)(vto + ((long)(bi * DIM + n)) * SEQ + i0) = o;
            }
        }
    }
}

// ---------------- attention: KV-SPLIT (blockIdx.z halves), fp32 partials ----
// grid (32, 16, 2) = 1024 blocks -> 4 blocks/CU, 16 waves/CU. Each block does
// 2048 kv, writes UNNORMALIZED fp32 O-partial + per-(half,head,row) l.
// No-max softmax makes the cross-half combine purely additive (done in oproj).
__global__ __launch_bounds__(256, 4) void attn_kernel(
    const unsigned short* __restrict__ qb, const unsigned short* __restrict__ kbuf,
    const unsigned short* __restrict__ vT,
    float* __restrict__ opart, float* __restrict__ lbuf) {
    __shared__ unsigned short K0[64 * 32], K1[64 * 32];
    __shared__ unsigned short V0[32 * 64], V1[32 * 64];
#if !HAVE_PLSWAP
    __shared__ unsigned short P[4][32][72];
#endif
    const int tid = threadIdx.x, lane = tid & 63, wave = tid >> 6;
    const int ql = lane & 15, quad = lane >> 4;
    const int bh = blockIdx.y, b = bh >> 3, h = bh & 7;
    const int half = blockIdx.z;
    const int kvb = half * (SEQ / 2);
    const int q0 = blockIdx.x * 128 + wave * 32;

    const unsigned short* qrow = qb   + (long)b * SEQ * DIM + h * HDIM;
    const unsigned short* krow = kbuf + (long)b * SEQ * DIM + h * HDIM;
    const unsigned short* vrow = vT   + (long)(b * DIM + h * HDIM) * SEQ;

    short8 qf[2];
#pragma unroll
    for (int t = 0; t < 2; t++)
        qf[t] = *(const short8*)(qrow + (long)(q0 + t*16 + ql) * DIM + quad*8);

    short8 ones;
#pragma unroll
    for (int i = 0; i < 8; i++) ones[i] = (short)0x3F80;

    const unsigned short* kg = krow + (long)(kvb + wave*16 + (lane >> 2)) * DIM
                                    + ((lane & 3) ^ ((lane >> 3) & 3)) * 8;
    const unsigned short* vg = vrow + (long)(wave*8 + (lane >> 3)) * SEQ + kvb
                                    + ((lane & 7) ^ (lane >> 3)) * 8;
    unsigned short* kd0 = K0 + wave * 512;  unsigned short* kd1 = K1 + wave * 512;
    unsigned short* vd0 = V0 + wave * 512;  unsigned short* vd1 = V1 + wave * 512;
    const int kro = (quad ^ ((ql >> 1) & 3)) * 8;   // K read chunk pos
    const int vmask = ql & 7;                        // V read xor key

    floatx4 acc[2][2] = {};    // Oᵀ accum [dim-tile][q-tile]
    floatx4 accL[2] = {};      // row-sums via ones-MFMA

    auto compute = [&](const unsigned short* Ks, const unsigned short* Vs) {
        unsigned pk[4][2][2];   // [mt][t][b32]: packed exp2(S) in C-layout
#pragma unroll
        for (int mt = 0; mt < 4; ++mt) {
            short8 kf = *(const short8*)(Ks + (mt*16 + ql) * 32 + kro);
#pragma unroll
            for (int t = 0; t < 2; t++) {
                floatx4 z = {};
                floatx4 s = __builtin_amdgcn_mfma_f32_16x16x32_bf16(kf, qf[t], z, 0, 0, 0);
                float p0 = __builtin_amdgcn_exp2f(s[0]);
                float p1 = __builtin_amdgcn_exp2f(s[1]);
                float p2 = __builtin_amdgcn_exp2f(s[2]);
                float p3 = __builtin_amdgcn_exp2f(s[3]);
                pk[mt][t][0] = pack2(p0, p1);
                pk[mt][t][1] = pack2(p2, p3);
#if !HAVE_PLSWAP
                uintx2 w; w.x = pk[mt][t][0]; w.y = pk[mt][t][1];
                *(uintx2*)(&P[wave][t*16 + ql][mt*16 + quad*4]) = w;
#endif
            }
        }
#pragma unroll
        for (int ks = 0; ks < 2; ++ks) {
            short8 pf[2];
#pragma unroll
            for (int t = 0; t < 2; t++) {
#if HAVE_PLSWAP
                uintx2 x0 = __builtin_amdgcn_permlane32_swap(pk[2*ks][t][0], pk[2*ks+1][t][0], false, false);
                uintx2 y0 = __builtin_amdgcn_permlane16_swap(x0.x, x0.y, false, false);
                uintx2 x1 = __builtin_amdgcn_permlane32_swap(pk[2*ks][t][1], pk[2*ks+1][t][1], false, false);
                uintx2 y1 = __builtin_amdgcn_permlane16_swap(x1.x, x1.y, false, false);
                uintx4 pv; pv.x = y0.x; pv.y = y1.x; pv.z = y0.y; pv.w = y1.y;
                pf[t] = *(short8*)&pv;
#else
                pf[t] = *(const short8*)(&P[wave][t*16 + ql][ks*32 + quad*8]);
#endif
            }
#pragma unroll
            for (int t = 0; t < 2; t++)
                accL[t] = __builtin_amdgcn_mfma_f32_16x16x32_bf16(ones, pf[t], accL[t], 0, 0, 0);
#pragma unroll
            for (int dt = 0; dt < 2; ++dt) {
                short8 vf = *(const short8*)(Vs + (dt*16 + ql) * 64 + ((ks*4 + quad) ^ vmask) * 8);
#pragma unroll
                for (int t = 0; t < 2; t++)
                    acc[dt][t] = __builtin_amdgcn_mfma_f32_16x16x32_bf16(vf, pf[t], acc[dt][t], 0, 0, 0);
            }
        }
    };

    g2l16(kg, kd0); g2l16(vg, vd0);
    __syncthreads();
    for (int it = 0; it < SEQ / 128; it += 2) {   // 32 iters of 64 kv (half range)
        if (it + 1 < SEQ / 128) {
            g2l16(kg + (long)(it + 1) * 64 * DIM, kd1);
            g2l16(vg + (it + 1) * 64, vd1);
        }
        compute(K0, V0);
        __syncthreads();
        if (it + 2 < SEQ / 128) {
            g2l16(kg + (long)(it + 2) * 64 * DIM, kd0);
            g2l16(vg + (it + 2) * 64, vd0);
        }
        compute(K1, V1);
        __syncthreads();
    }

    // store UNNORMALIZED fp32 partial O
    float* obase = opart + (long)half * ROWS * DIM;
#pragma unroll
    for (int dt = 0; dt < 2; dt++)
#pragma unroll
        for (int t = 0; t < 2; t++) {
            float4 o;
            o.x = acc[dt][t][0]; o.y = acc[dt][t][1];
            o.z = acc[dt][t][2]; o.w = acc[dt][t][3];
            *(float4*)(obase + (long)(b*SEQ + q0 + t*16 + ql) * DIM + h*HDIM + dt*16 + quad*4) = o;
        }
    // store partial row-sums l (one lane-quad's worth; all quads hold the same value)
    if (quad == 0) {
#pragma unroll
        for (int t = 0; t < 2; t++)
            lbuf[(long)(half * NHEAD + h) * ROWS + b*SEQ + q0 + t*16 + ql] = accL[t][0];
    }
}

// ---------------- output projection: combine halves + normalize + GEMM ------
__global__ __launch_bounds__(256, 2) void oproj_kernel(
    const float* __restrict__ opart, const float* __restrict__ lbuf,
    const unsigned short* __restrict__ W, const float* __restrict__ bias,
    float* __restrict__ out) {
    __shared__ unsigned short Abuf[8][64][32];
    const int tid = threadIdx.x, lane = tid & 63, wave = tid >> 6;
    const int ql = lane & 15, quad = lane >> 4;
    const int m0 = blockIdx.x * 64;

    {   // stage A = (O0+O1)/(l0+l1) as bf16, chunk-XOR swizzle. head = kb.
        const int row = tid >> 2, c8 = (tid & 3) * 8;
        const int swz = ((tid & 3) ^ ((row >> 1) & 3)) * 8;
        const float* s0 = opart + (long)(m0 + row) * DIM + c8;
        const float* s1 = s0 + (long)ROWS * DIM;
#pragma unroll
        for (int kb = 0; kb < 8; kb++) {
            float li = lbuf[(long)kb * ROWS + m0 + row]
                     + lbuf[(long)(NHEAD + kb) * ROWS + m0 + row];
            float r = __builtin_amdgcn_rcpf(li);
            float4 a0 = *(const float4*)(s0 + kb * 32);
            float4 a1 = *(const float4*)(s0 + kb * 32 + 4);
            float4 b0 = *(const float4*)(s1 + kb * 32);
            float4 b1 = *(const float4*)(s1 + kb * 32 + 4);
            ushort8 o;
            o[0] = f2bf((a0.x + b0.x) * r); o[1] = f2bf((a0.y + b0.y) * r);
            o[2] = f2bf((a0.z + b0.z) * r); o[3] = f2bf((a0.w + b0.w) * r);
            o[4] = f2bf((a1.x + b1.x) * r); o[5] = f2bf((a1.y + b1.y) * r);
            o[6] = f2bf((a1.z + b1.z) * r); o[7] = f2bf((a1.w + b1.w) * r);
            *(ushort8*)(&Abuf[kb][row][swz]) = o;
        }
    }
    __syncthreads();
    const int n0 = wave * 64;
    const int akey = (quad ^ ((ql >> 1) & 3)) * 8;
    floatx4 acc[4][4] = {};
    for (int kb = 0; kb < 8; kb++) {
        short8 wf[4], af[4];
#pragma unroll
        for (int u = 0; u < 4; u++)
            wf[u] = *(const short8*)(W + (long)(n0 + u*16 + ql) * DIM + kb*32 + quad*8);
#pragma unroll
        for (int t = 0; t < 4; t++)
            af[t] = *(const short8*)(&Abuf[kb][t*16 + ql][akey]);
#pragma unroll
        for (int t = 0; t < 4; t++)
#pragma unroll
            for (int u = 0; u < 4; u++)
                acc[t][u] = __builtin_amdgcn_mfma_f32_16x16x32_bf16(wf[u], af[t], acc[t][u], 0, 0, 0);
    }
#pragma unroll
    for (int t = 0; t < 4; t++) {
        int m = m0 + t*16 + ql;
#pragma unroll
        for (int u = 0; u < 4; u++) {
            int n = n0 + u*16 + quad*4;
            float4 b4 = *(const float4*)(bias + n);
            float4 o;
            o.x = acc[t][u][0] + b4.x;
            o.y = acc[t][u][1] + b4.y;
            o.z = acc[t][u][2] + b4.z;
            o.w = acc[t][u][3] + b4.w;
            *(float4*)(out + (long)m * DIM + n) = o;
        }
    }
}

extern "C" void kernel_launch(void* const* d_in, const int* in_sizes, int n_in,
                              void* d_out, int out_size, void* d_ws, size_t ws_size,
                              hipStream_t stream) {
    const float* x  = (const float*)d_in[0];
    const float* y  = (const float*)d_in[1];
    const float* Wq = (const float*)d_in[2];
    const float* bq = (const float*)d_in[3];
    const float* Wk = (const float*)d_in[4];
    const float* bk = (const float*)d_in[5];
    const float* Wv = (const float*)d_in[6];
    const float* bv = (const float*)d_in[7];
    const float* Wo = (const float*)d_in[8];
    const float* bo = (const float*)d_in[9];
    float* out = (float*)d_out;

    const long NX = (long)ROWS * DIM;   // 2097152
    const long NW = (long)DIM * DIM;    // 65536
    unsigned short* Wqb  = (unsigned short*)d_ws;
    unsigned short* Wkb  = Wqb + NW;
    unsigned short* Wvb  = Wkb + NW;
    unsigned short* Wob  = Wvb + NW;
    unsigned short* qbf  = Wob + NW;
    unsigned short* kbf  = qbf + NX;
    unsigned short* vTb  = kbf + NX;
    float* opart = (float*)(vTb + NX);  // 2 * NX fp32 = 16 MB
    float* lbuf  = opart + 2 * NX;      // 2*NHEAD*ROWS fp32 = 512 KB ; total ~29.2 MB

    convw_kernel<<<dim3(NW / 1024, 4), dim3(256), 0, stream>>>(
        Wq, Wk, Wv, Wo, Wqb, Wkb, Wvb, Wob);

    qkv_kernel<<<dim3(ROWS / 64, 3), dim3(256), 0, stream>>>(
        x, y, Wqb, Wkb, Wvb, bq, bk, bv, qbf, kbf, vTb);

    attn_kernel<<<dim3(SEQ / 128, BATCH * NHEAD, 2), dim3(256), 0, stream>>>(
        qbf, kbf, vTb, opart, lbuf);

    oproj_kernel<<<dim3(ROWS / 64), dim3(256), 0, stream>>>(
        opart, lbuf, Wob, bo, out);
}

// Round 8
// 154.222 us; speedup vs baseline: 1.2335x; 1.0317x over previous
//
#include <hip/hip_runtime.h>

#define BATCH 2
#define SEQ   4096
#define DIM   256
#define NHEAD 8
#define HDIM  32
#define ROWS  (BATCH * SEQ)   // 8192

typedef __attribute__((ext_vector_type(8))) short short8;
typedef __attribute__((ext_vector_type(8))) unsigned short ushort8;
typedef __attribute__((ext_vector_type(4))) unsigned short ushortx4;
typedef __attribute__((ext_vector_type(4))) float floatx4;
typedef __attribute__((ext_vector_type(2))) unsigned int uintx2;
typedef __attribute__((ext_vector_type(4))) unsigned int uintx4;

static __device__ __forceinline__ unsigned short f2bf(float f) {
    union { float f; unsigned u; } v; v.f = f;
    unsigned r = v.u + 0x7fffu + ((v.u >> 16) & 1u);   // RNE
    return (unsigned short)(r >> 16);
}
static __device__ __forceinline__ unsigned fbits(float f) {
    union { float f; unsigned u; } v; v.f = f; return v.u;
}
// pack two fp32 -> two bf16 (truncate) in ONE v_perm_b32
static __device__ __forceinline__ unsigned pack2(float a, float b) {
    return __builtin_amdgcn_perm(fbits(b), fbits(a), 0x07060302u);
}
// async global -> LDS: wave-uniform LDS base + lane*16
static __device__ __forceinline__ void g2l16(const void* g, void* l) {
    __builtin_amdgcn_global_load_lds(
        (const __attribute__((address_space(1))) unsigned int*)g,
        (__attribute__((address_space(3))) unsigned int*)l, 16, 0, 0);
}

#if __has_builtin(__builtin_amdgcn_permlane32_swap) && __has_builtin(__builtin_amdgcn_permlane16_swap)
#define HAVE_PLSWAP 1
#else
#define HAVE_PLSWAP 0
#endif

// ---------------- fp32 -> bf16 conversion of the 4 weight matrices ----------
__global__ __launch_bounds__(256) void convw_kernel(
    const float* __restrict__ W0, const float* __restrict__ W1,
    const float* __restrict__ W2, const float* __restrict__ W3,
    unsigned short* __restrict__ o0, unsigned short* __restrict__ o1,
    unsigned short* __restrict__ o2, unsigned short* __restrict__ o3) {
    const float* s; unsigned short* d;
    switch (blockIdx.y) {
        case 0:  s = W0; d = o0; break;
        case 1:  s = W1; d = o1; break;
        case 2:  s = W2; d = o2; break;
        default: s = W3; d = o3; break;
    }
    long off = ((long)blockIdx.x * 256 + threadIdx.x) * 4;
    float4 v = *(const float4*)(s + off);
    ushortx4 o;
    o.x = f2bf(v.x); o.y = f2bf(v.y); o.z = f2bf(v.z); o.w = f2bf(v.w);
    *(ushortx4*)(d + off) = o;
}

// ---------------- fused QKV projection (kb-loop fully unrolled) -------------
__global__ __launch_bounds__(256, 2) void qkv_kernel(
    const float* __restrict__ x, const float* __restrict__ y,
    const unsigned short* __restrict__ Wq, const unsigned short* __restrict__ Wk,
    const unsigned short* __restrict__ Wv,
    const float* __restrict__ bq, const float* __restrict__ bk, const float* __restrict__ bv,
    unsigned short* __restrict__ qo, unsigned short* __restrict__ ko,
    unsigned short* __restrict__ vto) {
    __shared__ unsigned short Abuf[8][64][32];
    const int tid = threadIdx.x, lane = tid & 63, wave = tid >> 6;
    const int ql = lane & 15, quad = lane >> 4;
    const int mat = blockIdx.y;
    const int m0 = blockIdx.x * 64;
    const float* A = (mat == 0) ? x : y;
    const unsigned short* W = (mat == 0) ? Wq : (mat == 1) ? Wk : Wv;
    const float* bias = (mat == 0) ? bq : (mat == 1) ? bk : bv;

    {   // stage full 64x256 A tile, fp32 -> bf16, chunk-XOR swizzle
        const int row = tid >> 2, c8 = (tid & 3) * 8;
        const int swz = ((tid & 3) ^ ((row >> 1) & 3)) * 8;
        const float* src = A + (long)(m0 + row) * DIM + c8;
#pragma unroll
        for (int kb = 0; kb < 8; kb++) {
            float4 v0 = *(const float4*)(src + kb * 32);
            float4 v1 = *(const float4*)(src + kb * 32 + 4);
            ushort8 o;
            o[0] = f2bf(v0.x); o[1] = f2bf(v0.y); o[2] = f2bf(v0.z); o[3] = f2bf(v0.w);
            o[4] = f2bf(v1.x); o[5] = f2bf(v1.y); o[6] = f2bf(v1.z); o[7] = f2bf(v1.w);
            *(ushort8*)(&Abuf[kb][row][swz]) = o;
        }
    }
    __syncthreads();
    const int n0 = wave * 64;
    const int akey = (quad ^ ((ql >> 1) & 3)) * 8;
    floatx4 acc[4][4] = {};
#pragma unroll
    for (int kb = 0; kb < 8; kb++) {
        short8 wf[4], af[4];
#pragma unroll
        for (int u = 0; u < 4; u++)
            wf[u] = *(const short8*)(W + (long)(n0 + u*16 + ql) * DIM + kb*32 + quad*8);
#pragma unroll
        for (int t = 0; t < 4; t++)
            af[t] = *(const short8*)(&Abuf[kb][t*16 + ql][akey]);
        if (mat < 2) {
#pragma unroll
            for (int t = 0; t < 4; t++)
#pragma unroll
                for (int u = 0; u < 4; u++)
                    acc[t][u] = __builtin_amdgcn_mfma_f32_16x16x32_bf16(wf[u], af[t], acc[t][u], 0, 0, 0);
        } else {
#pragma unroll
            for (int t = 0; t < 4; t++)
#pragma unroll
                for (int u = 0; u < 4; u++)
                    acc[t][u] = __builtin_amdgcn_mfma_f32_16x16x32_bf16(af[t], wf[u], acc[t][u], 0, 0, 0);
        }
    }
    if (mat < 2) {
        const float scale = (mat == 0) ? 0.09016844005556021f : 1.0f;
        unsigned short* out = (mat == 0) ? qo : ko;
#pragma unroll
        for (int t = 0; t < 4; t++) {
            int m = m0 + t*16 + ql;
#pragma unroll
            for (int u = 0; u < 4; u++) {
                int n = n0 + u*16 + quad*4;
                float4 b4 = *(const float4*)(bias + n);
                ushortx4 o;
                o.x = f2bf((acc[t][u][0] + b4.x) * scale);
                o.y = f2bf((acc[t][u][1] + b4.y) * scale);
                o.z = f2bf((acc[t][u][2] + b4.z) * scale);
                o.w = f2bf((acc[t][u][3] + b4.w) * scale);
                *(ushortx4*)(out + (long)m * DIM + n) = o;
            }
        }
    } else {
#pragma unroll
        for (int t = 0; t < 4; t++) {
            int mb = m0 + t*16 + quad*4;
            int bi = mb >> 12, i0 = mb & (SEQ - 1);
#pragma unroll
            for (int u = 0; u < 4; u++) {
                int n = n0 + u*16 + ql;
                float b = bias[n];
                ushortx4 o;
                o.x = f2bf(acc[t][u][0] + b);
                o.y = f2bf(acc[t][u][1] + b);
                o.z = f2bf(acc[t][u][2] + b);
                o.w = f2bf(acc[t][u][3] + b);
                *(ushortx4*)(vto + ((long)(bi * DIM + n)) * SEQ + i0) = o;
            }
        }
    }
}

// ---------------- attention: KV-split x NSPLIT, fp32 unnormalized partials --
template<int NSPLIT>
__global__ __launch_bounds__(256, 4) void attn_kernel(
    const unsigned short* __restrict__ qb, const unsigned short* __restrict__ kbuf,
    const unsigned short* __restrict__ vT,
    float* __restrict__ opart, float* __restrict__ lbuf) {
    __shared__ unsigned short K0[64 * 32], K1[64 * 32];
    __shared__ unsigned short V0[32 * 64], V1[32 * 64];
#if !HAVE_PLSWAP
    __shared__ unsigned short P[4][32][72];
#endif
    const int tid = threadIdx.x, lane = tid & 63, wave = tid >> 6;
    const int ql = lane & 15, quad = lane >> 4;
    const int bh = blockIdx.y, b = bh >> 3, h = bh & 7;
    const int part = blockIdx.z;
    const int kvb = part * (SEQ / NSPLIT);
    const int q0 = blockIdx.x * 128 + wave * 32;

    const unsigned short* qrow = qb   + (long)b * SEQ * DIM + h * HDIM;
    const unsigned short* krow = kbuf + (long)b * SEQ * DIM + h * HDIM;
    const unsigned short* vrow = vT   + (long)(b * DIM + h * HDIM) * SEQ;

    short8 qf[2];
#pragma unroll
    for (int t = 0; t < 2; t++)
        qf[t] = *(const short8*)(qrow + (long)(q0 + t*16 + ql) * DIM + quad*8);

    short8 ones;
#pragma unroll
    for (int i = 0; i < 8; i++) ones[i] = (short)0x3F80;

    const unsigned short* kg = krow + (long)(kvb + wave*16 + (lane >> 2)) * DIM
                                    + ((lane & 3) ^ ((lane >> 3) & 3)) * 8;
    const unsigned short* vg = vrow + (long)(wave*8 + (lane >> 3)) * SEQ + kvb
                                    + ((lane & 7) ^ (lane >> 3)) * 8;
    unsigned short* kd0 = K0 + wave * 512;  unsigned short* kd1 = K1 + wave * 512;
    unsigned short* vd0 = V0 + wave * 512;  unsigned short* vd1 = V1 + wave * 512;
    const int kro = (quad ^ ((ql >> 1) & 3)) * 8;   // K read chunk pos
    const int vmask = ql & 7;                        // V read xor key

    floatx4 acc[2][2] = {};    // Oᵀ accum [dim-tile][q-tile]
    floatx4 accL[2] = {};      // row-sums via ones-MFMA

    auto compute = [&](const unsigned short* Ks, const unsigned short* Vs) {
        unsigned pk[4][2][2];   // [mt][t][b32]: packed exp2(S) in C-layout
#pragma unroll
        for (int mt = 0; mt < 4; ++mt) {
            short8 kf = *(const short8*)(Ks + (mt*16 + ql) * 32 + kro);
#pragma unroll
            for (int t = 0; t < 2; t++) {
                floatx4 z = {};
                floatx4 s = __builtin_amdgcn_mfma_f32_16x16x32_bf16(kf, qf[t], z, 0, 0, 0);
                float p0 = __builtin_amdgcn_exp2f(s[0]);
                float p1 = __builtin_amdgcn_exp2f(s[1]);
                float p2 = __builtin_amdgcn_exp2f(s[2]);
                float p3 = __builtin_amdgcn_exp2f(s[3]);
                pk[mt][t][0] = pack2(p0, p1);
                pk[mt][t][1] = pack2(p2, p3);
#if !HAVE_PLSWAP
                uintx2 w; w.x = pk[mt][t][0]; w.y = pk[mt][t][1];
                *(uintx2*)(&P[wave][t*16 + ql][mt*16 + quad*4]) = w;
#endif
            }
        }
#pragma unroll
        for (int ks = 0; ks < 2; ++ks) {
            short8 pf[2];
#pragma unroll
            for (int t = 0; t < 2; t++) {
#if HAVE_PLSWAP
                uintx2 x0 = __builtin_amdgcn_permlane32_swap(pk[2*ks][t][0], pk[2*ks+1][t][0], false, false);
                uintx2 y0 = __builtin_amdgcn_permlane16_swap(x0.x, x0.y, false, false);
                uintx2 x1 = __builtin_amdgcn_permlane32_swap(pk[2*ks][t][1], pk[2*ks+1][t][1], false, false);
                uintx2 y1 = __builtin_amdgcn_permlane16_swap(x1.x, x1.y, false, false);
                uintx4 pv; pv.x = y0.x; pv.y = y1.x; pv.z = y0.y; pv.w = y1.y;
                pf[t] = *(short8*)&pv;
#else
                pf[t] = *(const short8*)(&P[wave][t*16 + ql][ks*32 + quad*8]);
#endif
            }
#pragma unroll
            for (int t = 0; t < 2; t++)
                accL[t] = __builtin_amdgcn_mfma_f32_16x16x32_bf16(ones, pf[t], accL[t], 0, 0, 0);
#pragma unroll
            for (int dt = 0; dt < 2; ++dt) {
                short8 vf = *(const short8*)(Vs + (dt*16 + ql) * 64 + ((ks*4 + quad) ^ vmask) * 8);
#pragma unroll
                for (int t = 0; t < 2; t++)
                    acc[dt][t] = __builtin_amdgcn_mfma_f32_16x16x32_bf16(vf, pf[t], acc[dt][t], 0, 0, 0);
            }
        }
    };

    g2l16(kg, kd0); g2l16(vg, vd0);
    __syncthreads();
    const int NIT = SEQ / 64 / NSPLIT;
    for (int it = 0; it < NIT; it += 2) {
        if (it + 1 < NIT) {
            g2l16(kg + (long)(it + 1) * 64 * DIM, kd1);
            g2l16(vg + (it + 1) * 64, vd1);
        }
        compute(K0, V0);
        __syncthreads();
        if (it + 2 < NIT) {
            g2l16(kg + (long)(it + 2) * 64 * DIM, kd0);
            g2l16(vg + (it + 2) * 64, vd0);
        }
        compute(K1, V1);
        __syncthreads();
    }

    // store UNNORMALIZED fp32 partial O
    float* obase = opart + (long)part * ROWS * DIM;
#pragma unroll
    for (int dt = 0; dt < 2; dt++)
#pragma unroll
        for (int t = 0; t < 2; t++) {
            float4 o;
            o.x = acc[dt][t][0]; o.y = acc[dt][t][1];
            o.z = acc[dt][t][2]; o.w = acc[dt][t][3];
            *(float4*)(obase + (long)(b*SEQ + q0 + t*16 + ql) * DIM + h*HDIM + dt*16 + quad*4) = o;
        }
    if (quad == 0) {
#pragma unroll
        for (int t = 0; t < 2; t++)
            lbuf[(long)(part * NHEAD + h) * ROWS + b*SEQ + q0 + t*16 + ql] = accL[t][0];
    }
}

// ---------------- output projection: combine partials + normalize + GEMM ----
template<int NSPLIT>
__global__ __launch_bounds__(256, 2) void oproj_kernel(
    const float* __restrict__ opart, const float* __restrict__ lbuf,
    const unsigned short* __restrict__ W, const float* __restrict__ bias,
    float* __restrict__ out) {
    __shared__ unsigned short Abuf[8][64][32];
    const int tid = threadIdx.x, lane = tid & 63, wave = tid >> 6;
    const int ql = lane & 15, quad = lane >> 4;
    const int m0 = blockIdx.x * 64;

    {   // stage A = (sum O_i)/(sum l_i) as bf16, chunk-XOR swizzle. head = kb.
        const int row = tid >> 2, c8 = (tid & 3) * 8;
        const int swz = ((tid & 3) ^ ((row >> 1) & 3)) * 8;
        const float* s0 = opart + (long)(m0 + row) * DIM + c8;
#pragma unroll
        for (int kb = 0; kb < 8; kb++) {
            float li = 0.f;
#pragma unroll
            for (int i = 0; i < NSPLIT; i++)
                li += lbuf[(long)(i * NHEAD + kb) * ROWS + m0 + row];
            float r = __builtin_amdgcn_rcpf(li);
            float a[8] = {};
#pragma unroll
            for (int i = 0; i < NSPLIT; i++) {
                const float* si = s0 + (long)i * ROWS * DIM;
                float4 a0 = *(const float4*)(si + kb * 32);
                float4 a1 = *(const float4*)(si + kb * 32 + 4);
                a[0] += a0.x; a[1] += a0.y; a[2] += a0.z; a[3] += a0.w;
                a[4] += a1.x; a[5] += a1.y; a[6] += a1.z; a[7] += a1.w;
            }
            ushort8 o;
#pragma unroll
            for (int e = 0; e < 8; e++) o[e] = f2bf(a[e] * r);
            *(ushort8*)(&Abuf[kb][row][swz]) = o;
        }
    }
    __syncthreads();
    const int n0 = wave * 64;
    const int akey = (quad ^ ((ql >> 1) & 3)) * 8;
    floatx4 acc[4][4] = {};
#pragma unroll
    for (int kb = 0; kb < 8; kb++) {
        short8 wf[4], af[4];
#pragma unroll
        for (int u = 0; u < 4; u++)
            wf[u] = *(const short8*)(W + (long)(n0 + u*16 + ql) * DIM + kb*32 + quad*8);
#pragma unroll
        for (int t = 0; t < 4; t++)
            af[t] = *(const short8*)(&Abuf[kb][t*16 + ql][akey]);
#pragma unroll
        for (int t = 0; t < 4; t++)
#pragma unroll
            for (int u = 0; u < 4; u++)
                acc[t][u] = __builtin_amdgcn_mfma_f32_16x16x32_bf16(wf[u], af[t], acc[t][u], 0, 0, 0);
    }
#pragma unroll
    for (int t = 0; t < 4; t++) {
        int m = m0 + t*16 + ql;
#pragma unroll
        for (int u = 0; u < 4; u++) {
            int n = n0 + u*16 + quad*4;
            float4 b4 = *(const float4*)(bias + n);
            float4 o;
            o.x = acc[t][u][0] + b4.x;
            o.y = acc[t][u][1] + b4.y;
            o.z = acc[t][u][2] + b4.z;
            o.w = acc[t][u][3] + b4.w;
            *(float4*)(out + (long)m * DIM + n) = o;
        }
    }
}

extern "C" void kernel_launch(void* const* d_in, const int* in_sizes, int n_in,
                              void* d_out, int out_size, void* d_ws, size_t ws_size,
                              hipStream_t stream) {
    const float* x  = (const float*)d_in[0];
    const float* y  = (const float*)d_in[1];
    const float* Wq = (const float*)d_in[2];
    const float* bq = (const float*)d_in[3];
    const float* Wk = (const float*)d_in[4];
    const float* bk = (const float*)d_in[5];
    const float* Wv = (const float*)d_in[6];
    const float* bv = (const float*)d_in[7];
    const float* Wo = (const float*)d_in[8];
    const float* bo = (const float*)d_in[9];
    float* out = (float*)d_out;

    const long NX = (long)ROWS * DIM;   // 2097152
    const long NW = (long)DIM * DIM;    // 65536
    unsigned short* Wqb  = (unsigned short*)d_ws;
    unsigned short* Wkb  = Wqb + NW;
    unsigned short* Wvb  = Wkb + NW;
    unsigned short* Wob  = Wvb + NW;
    unsigned short* qbf  = Wob + NW;
    unsigned short* kbf  = qbf + NX;
    unsigned short* vTb  = kbf + NX;
    float* opart = (float*)(vTb + NX);
    // bytes used so far: (4*NW + 3*NX)*2 ≈ 13.1 MB
    const size_t base = (size_t)(4*NW + 3*NX) * 2;
    const size_t need4 = base + (size_t)(4*NX + 4*NHEAD*ROWS) * 4;   // ~47.7 MB

    convw_kernel<<<dim3(NW / 1024, 4), dim3(256), 0, stream>>>(
        Wq, Wk, Wv, Wo, Wqb, Wkb, Wvb, Wob);

    qkv_kernel<<<dim3(ROWS / 64, 3), dim3(256), 0, stream>>>(
        x, y, Wqb, Wkb, Wvb, bq, bk, bv, qbf, kbf, vTb);

    if (ws_size >= need4) {
        float* lbuf = opart + 4 * NX;
        attn_kernel<4><<<dim3(SEQ / 128, BATCH * NHEAD, 4), dim3(256), 0, stream>>>(
            qbf, kbf, vTb, opart, lbuf);
        oproj_kernel<4><<<dim3(ROWS / 64), dim3(256), 0, stream>>>(
            opart, lbuf, Wob, bo, out);
    } else {
        float* lbuf = opart + 2 * NX;
        attn_kernel<2><<<dim3(SEQ / 128, BATCH * NHEAD, 2), dim3(256), 0, stream>>>(
            qbf, kbf, vTb, opart, lbuf);
        oproj_kernel<2><<<dim3(ROWS / 64), dim3(256), 0, stream>>>(
            opart, lbuf, Wob, bo, out);
    }
}